// Round 1
// baseline (29.340 us; speedup 1.0000x reference)
//
#include <hip/hip_runtime.h>

#define NBLOCKS 2048
#define NTHREADS 256

__device__ __forceinline__ float wave_reduce_sum(float v) {
    #pragma unroll
    for (int off = 32; off > 0; off >>= 1)
        v += __shfl_down(v, off, 64);
    return v;
}

__device__ __forceinline__ float sample_loss(float p0, float p1, float p2, int lab) {
    // per_sample = lse - (eps/C)*(p0+p1+p2) - (1-eps)*p_lab ; return w[lab]*per_sample
    float m = fmaxf(p0, fmaxf(p1, p2));
    float e = __expf(p0 - m) + __expf(p1 - m) + __expf(p2 - m);
    float lse = m + __logf(e);
    float pl = (lab == 0) ? p0 : ((lab == 1) ? p1 : p2);
    float w  = (lab == 0) ? 10.0f : ((lab == 1) ? (10.0f / 3.0f) : (10.0f / 6.0f));
    float per = lse - (0.1f / 3.0f) * (p0 + p1 + p2) - 0.9f * pl;
    return w * per;
}

__global__ void __launch_bounds__(NTHREADS, 8)
ce_partial_kernel(const float* __restrict__ pred,
                  const int* __restrict__ label,
                  float* __restrict__ partials, int n) {
    int tid = blockIdx.x * blockDim.x + threadIdx.x;
    int nthreads = gridDim.x * blockDim.x;
    int groups = n >> 2;  // 4 samples per group
    float acc = 0.0f;

    for (int g = tid; g < groups; g += nthreads) {
        const float4* p4 = reinterpret_cast<const float4*>(pred + (size_t)g * 12);
        float4 a = p4[0];
        float4 b = p4[1];
        float4 c = p4[2];
        int4 l = reinterpret_cast<const int4*>(label)[g];
        acc += sample_loss(a.x, a.y, a.z, l.x);
        acc += sample_loss(a.w, b.x, b.y, l.y);
        acc += sample_loss(b.z, b.w, c.x, l.z);
        acc += sample_loss(c.y, c.z, c.w, l.w);
    }
    // tail (n % 4 != 0) — handled by global thread 0 only (N=8388608 -> no-op)
    if (tid == 0) {
        for (int i = groups << 2; i < n; ++i) {
            acc += sample_loss(pred[(size_t)i * 3], pred[(size_t)i * 3 + 1],
                               pred[(size_t)i * 3 + 2], label[i]);
        }
    }

    __shared__ float sdata[NTHREADS / 64];
    float wsum = wave_reduce_sum(acc);
    int lane = threadIdx.x & 63;
    int wid = threadIdx.x >> 6;
    if (lane == 0) sdata[wid] = wsum;
    __syncthreads();
    if (threadIdx.x == 0) {
        float s = 0.0f;
        #pragma unroll
        for (int i = 0; i < NTHREADS / 64; ++i) s += sdata[i];
        partials[blockIdx.x] = s;
    }
}

__global__ void __launch_bounds__(256)
ce_final_kernel(const float* __restrict__ partials, int nparts,
                float* __restrict__ out, float inv_n) {
    float acc = 0.0f;
    for (int i = threadIdx.x; i < nparts; i += 256) acc += partials[i];
    __shared__ float sdata[4];
    float wsum = wave_reduce_sum(acc);
    int lane = threadIdx.x & 63;
    int wid = threadIdx.x >> 6;
    if (lane == 0) sdata[wid] = wsum;
    __syncthreads();
    if (threadIdx.x == 0) {
        float s = sdata[0] + sdata[1] + sdata[2] + sdata[3];
        out[0] = s * inv_n;
    }
}

extern "C" void kernel_launch(void* const* d_in, const int* in_sizes, int n_in,
                              void* d_out, int out_size, void* d_ws, size_t ws_size,
                              hipStream_t stream) {
    const float* pred = (const float*)d_in[0];
    const int* label = (const int*)d_in[1];
    int n = in_sizes[1];  // number of samples (pred is n*3)
    float* partials = (float*)d_ws;
    float* out = (float*)d_out;

    ce_partial_kernel<<<NBLOCKS, NTHREADS, 0, stream>>>(pred, label, partials, n);
    ce_final_kernel<<<1, 256, 0, stream>>>(partials, NBLOCKS, out, 1.0f / (float)n);
}